// Round 11
// baseline (330.901 us; speedup 1.0000x reference)
//
#include <hip/hip_runtime.h>
#include <hip/hip_bf16.h>
#include <cstdint>
#include <cstddef>

#define BDIM 32768
#define IDIM 512
#define ODIM 512
#define KDIM 1024   // I+O
#define NDIM 2048   // 4*O

typedef __attribute__((ext_vector_type(8))) __bf16 bf16x8;
typedef __attribute__((ext_vector_type(4))) float f32x4;
typedef __attribute__((ext_vector_type(8))) unsigned short u16x8;

__device__ __forceinline__ unsigned short f2bf(float x) {
  union { float f; uint32_t u; } v; v.f = x;
  uint32_t r = v.u + 0x7FFFu + ((v.u >> 16) & 1u);  // RNE
  return (unsigned short)(r >> 16);
}

__device__ __forceinline__ float bf2f(unsigned short s) {
  union { uint32_t u; float f; } v; v.u = ((uint32_t)s) << 16;
  return v.f;
}

// ---------------- pack kernel: W f32 -> bf16 ----------------

__global__ __launch_bounds__(256) void pack_w_kernel(const float* __restrict__ Wsrc,
                                                     unsigned short* __restrict__ Wb) {
  size_t t = (size_t)blockIdx.x * 256 + threadIdx.x;
  size_t e = t * 8;
  float4 v0 = ((const float4*)(Wsrc + e))[0];
  float4 v1 = ((const float4*)(Wsrc + e))[1];
  u16x8 r;
  r[0] = f2bf(v0.x); r[1] = f2bf(v0.y); r[2] = f2bf(v0.z); r[3] = f2bf(v0.w);
  r[4] = f2bf(v1.x); r[5] = f2bf(v1.y); r[6] = f2bf(v1.z); r[7] = f2bf(v1.w);
  *(u16x8*)(Wb + e) = r;
}

// ---------------- GEMM: R3 core (256x256, BK=32, ring-4) + fused f32 A-staging ----------------
// 8 waves (2M x 4N), per-wave 128x64 = acc[8][4] f32x4. Ring of 4 x 32KB LDS
// buffers, row-major [row][32 elems] with XOR-chunk swizzle (R3 champion,
// 152us). A is NOT pre-packed: staging loads f32 from input/h (concat at col
// 512; 8-col chunks never straddle), converts RNE to bf16, ds_write_b128 to
// the exact bytes gll would have written. B stays global_load_lds from
// pre-packed bf16 W. Sync: compiler-inserted vmcnt for the cvt data-dep each
// tile retires that tile's A-loads AND the 2-tile-old B-glls before the P1
// barrier -> cross-wave visibility of B(t) established at t-2. Hand VMW only
// at prologue end and tail t29.

#define BUFSZ 32768
#define ABYTES 16384

#define BAR() do { asm volatile("" ::: "memory"); __builtin_amdgcn_s_barrier(); asm volatile("" ::: "memory"); } while (0)
#define VMW(n) asm volatile("s_waitcnt vmcnt(" #n ")" ::: "memory")
#define LGKM0() do { asm volatile("s_waitcnt lgkmcnt(0)" ::: "memory"); __builtin_amdgcn_sched_barrier(0); } while (0)

__device__ __forceinline__ void gll16(const unsigned short* src, char* ldsdst) {
  __builtin_amdgcn_global_load_lds(
      (const __attribute__((address_space(1))) void*)src,
      (__attribute__((address_space(3))) void*)ldsdst, 16, 0, 0);
}

__device__ __forceinline__ u16x8 cvt8(float4 lo, float4 hi) {
  u16x8 w;
  w[0] = f2bf(lo.x); w[1] = f2bf(lo.y); w[2] = f2bf(lo.z); w[3] = f2bf(lo.w);
  w[4] = f2bf(hi.x); w[5] = f2bf(hi.y); w[6] = f2bf(hi.z); w[7] = f2bf(hi.w);
  return w;
}

template<int BUF, bool STG, bool TVMW>
__device__ __forceinline__ void tile_body(char* smem,
                                          const float* qi0, const float* qh0,
                                          const float* qi1, const float* qh1,
                                          const unsigned short* sB0, const unsigned short* sB1,
                                          int kstg, int wave1024, int wl16,
                                          int aoff, int boff, f32x4 (&acc)[8][4]) {
  char* const Ab = smem + BUF * BUFSZ;
  char* const Bb = Ab + ABYTES;
  constexpr int DB = ((BUF + 3) & 3) * BUFSZ;

  if (TVMW) VMW(0);
  BAR();

  // ---- phase 0: compute-reads A0-3 + B0-3; issue f32 A-loads for tile t+3 ----
  bf16x8 x0 = *(const bf16x8*)(Ab + aoff + 0 * 1024);
  bf16x8 x1 = *(const bf16x8*)(Ab + aoff + 1 * 1024);
  bf16x8 x2 = *(const bf16x8*)(Ab + aoff + 2 * 1024);
  bf16x8 x3 = *(const bf16x8*)(Ab + aoff + 3 * 1024);
  bf16x8 b0 = *(const bf16x8*)(Bb + boff + 0 * 1024);
  bf16x8 b1 = *(const bf16x8*)(Bb + boff + 1 * 1024);
  bf16x8 b2 = *(const bf16x8*)(Bb + boff + 2 * 1024);
  bf16x8 b3 = *(const bf16x8*)(Bb + boff + 3 * 1024);
  float4 al0, al1, ah0, ah1;
  if (STG) {
    const float* s0 = (kstg < 512) ? (qi0 + kstg) : (qh0 + (kstg - 512));
    const float* s1 = (kstg < 512) ? (qi1 + kstg) : (qh1 + (kstg - 512));
    al0 = ((const float4*)s0)[0]; al1 = ((const float4*)s0)[1];
    ah0 = ((const float4*)s1)[0]; ah1 = ((const float4*)s1)[1];
  }
  BAR();
  __builtin_amdgcn_sched_barrier(0);
  __builtin_amdgcn_s_setprio(1);
  acc[0][0] = __builtin_amdgcn_mfma_f32_16x16x32_bf16(x0, b0, acc[0][0], 0, 0, 0);
  acc[0][1] = __builtin_amdgcn_mfma_f32_16x16x32_bf16(x0, b1, acc[0][1], 0, 0, 0);
  acc[0][2] = __builtin_amdgcn_mfma_f32_16x16x32_bf16(x0, b2, acc[0][2], 0, 0, 0);
  acc[0][3] = __builtin_amdgcn_mfma_f32_16x16x32_bf16(x0, b3, acc[0][3], 0, 0, 0);
  acc[1][0] = __builtin_amdgcn_mfma_f32_16x16x32_bf16(x1, b0, acc[1][0], 0, 0, 0);
  acc[1][1] = __builtin_amdgcn_mfma_f32_16x16x32_bf16(x1, b1, acc[1][1], 0, 0, 0);
  acc[1][2] = __builtin_amdgcn_mfma_f32_16x16x32_bf16(x1, b2, acc[1][2], 0, 0, 0);
  acc[1][3] = __builtin_amdgcn_mfma_f32_16x16x32_bf16(x1, b3, acc[1][3], 0, 0, 0);
  acc[2][0] = __builtin_amdgcn_mfma_f32_16x16x32_bf16(x2, b0, acc[2][0], 0, 0, 0);
  acc[2][1] = __builtin_amdgcn_mfma_f32_16x16x32_bf16(x2, b1, acc[2][1], 0, 0, 0);
  acc[2][2] = __builtin_amdgcn_mfma_f32_16x16x32_bf16(x2, b2, acc[2][2], 0, 0, 0);
  acc[2][3] = __builtin_amdgcn_mfma_f32_16x16x32_bf16(x2, b3, acc[2][3], 0, 0, 0);
  acc[3][0] = __builtin_amdgcn_mfma_f32_16x16x32_bf16(x3, b0, acc[3][0], 0, 0, 0);
  acc[3][1] = __builtin_amdgcn_mfma_f32_16x16x32_bf16(x3, b1, acc[3][1], 0, 0, 0);
  acc[3][2] = __builtin_amdgcn_mfma_f32_16x16x32_bf16(x3, b2, acc[3][2], 0, 0, 0);
  acc[3][3] = __builtin_amdgcn_mfma_f32_16x16x32_bf16(x3, b3, acc[3][3], 0, 0, 0);
  __builtin_amdgcn_s_setprio(0);
  __builtin_amdgcn_sched_barrier(0);
  BAR();

  // ---- phase 1: compute-reads A4-7; B glls; A cvt + ds_write (tile t+3) ----
  x0 = *(const bf16x8*)(Ab + aoff + 4 * 1024);
  x1 = *(const bf16x8*)(Ab + aoff + 5 * 1024);
  x2 = *(const bf16x8*)(Ab + aoff + 6 * 1024);
  x3 = *(const bf16x8*)(Ab + aoff + 7 * 1024);
  if (STG) {
    gll16(sB0, smem + DB + ABYTES + wave1024);
    gll16(sB1, smem + DB + ABYTES + 8192 + wave1024);
    *(u16x8*)(smem + DB + wl16)        = cvt8(al0, al1);
    *(u16x8*)(smem + DB + 8192 + wl16) = cvt8(ah0, ah1);
  }
  BAR();
  __builtin_amdgcn_sched_barrier(0);
  __builtin_amdgcn_s_setprio(1);
  acc[4][0] = __builtin_amdgcn_mfma_f32_16x16x32_bf16(x0, b0, acc[4][0], 0, 0, 0);
  acc[4][1] = __builtin_amdgcn_mfma_f32_16x16x32_bf16(x0, b1, acc[4][1], 0, 0, 0);
  acc[4][2] = __builtin_amdgcn_mfma_f32_16x16x32_bf16(x0, b2, acc[4][2], 0, 0, 0);
  acc[4][3] = __builtin_amdgcn_mfma_f32_16x16x32_bf16(x0, b3, acc[4][3], 0, 0, 0);
  acc[5][0] = __builtin_amdgcn_mfma_f32_16x16x32_bf16(x1, b0, acc[5][0], 0, 0, 0);
  acc[5][1] = __builtin_amdgcn_mfma_f32_16x16x32_bf16(x1, b1, acc[5][1], 0, 0, 0);
  acc[5][2] = __builtin_amdgcn_mfma_f32_16x16x32_bf16(x1, b2, acc[5][2], 0, 0, 0);
  acc[5][3] = __builtin_amdgcn_mfma_f32_16x16x32_bf16(x1, b3, acc[5][3], 0, 0, 0);
  acc[6][0] = __builtin_amdgcn_mfma_f32_16x16x32_bf16(x2, b0, acc[6][0], 0, 0, 0);
  acc[6][1] = __builtin_amdgcn_mfma_f32_16x16x32_bf16(x2, b1, acc[6][1], 0, 0, 0);
  acc[6][2] = __builtin_amdgcn_mfma_f32_16x16x32_bf16(x2, b2, acc[6][2], 0, 0, 0);
  acc[6][3] = __builtin_amdgcn_mfma_f32_16x16x32_bf16(x2, b3, acc[6][3], 0, 0, 0);
  acc[7][0] = __builtin_amdgcn_mfma_f32_16x16x32_bf16(x3, b0, acc[7][0], 0, 0, 0);
  acc[7][1] = __builtin_amdgcn_mfma_f32_16x16x32_bf16(x3, b1, acc[7][1], 0, 0, 0);
  acc[7][2] = __builtin_amdgcn_mfma_f32_16x16x32_bf16(x3, b2, acc[7][2], 0, 0, 0);
  acc[7][3] = __builtin_amdgcn_mfma_f32_16x16x32_bf16(x3, b3, acc[7][3], 0, 0, 0);
  __builtin_amdgcn_s_setprio(0);
  __builtin_amdgcn_sched_barrier(0);
  // no trailing barrier: next tile's top barrier covers it
}

__global__ __launch_bounds__(512, 2) void gemm_kernel(const float* __restrict__ in_,
                                                      const float* __restrict__ hp,
                                                      const unsigned short* __restrict__ Bt,
                                                      unsigned short* __restrict__ Cz) {
  extern __shared__ char smem[];
  const int tid = threadIdx.x;
  const int wave = tid >> 6;
  const int lane = tid & 63;

  // XCD swizzle: each XCD gets a 16-mtile x 8-ntile chunk (B panel L2-resident)
  const int bid = blockIdx.x;                       // 0..1023
  const int swz = (bid & 7) * 128 + (bid >> 3);
  const int m0 = (swz >> 3) * 256;
  const int n0 = (swz & 7) * 256;

  const int wm = (wave >> 1) * 64;  // (kept for epilogue mapping below)
  const int wmR = (wave >> 2) * 128;
  const int wn = (wave & 3) * 64;
  const int lrow = lane & 15;
  const int cswz16 = (((lane >> 4) ^ (lrow >> 2)) & 3) * 16;
  const int aoff = (wmR + lrow) * 64 + cswz16;
  const int boff = (wn + lrow) * 64 + cswz16;
  const int wave1024 = wave * 1024;
  const int wl16 = wave1024 + lane * 16;

  // staging sources (pre-swizzled): thread covers rows r0, r1 with col-chunk c
  const int r0 = tid >> 2;
  const int r1 = r0 + 128;
  const int c0 = (tid & 3) ^ ((r0 >> 2) & 3);
  const int c1 = (tid & 3) ^ ((r1 >> 2) & 3);
  const float* qi0 = in_ + (size_t)(m0 + r0) * IDIM + c0 * 8;
  const float* qh0 = hp  + (size_t)(m0 + r0) * ODIM + c0 * 8;
  const float* qi1 = in_ + (size_t)(m0 + r1) * IDIM + c1 * 8;
  const float* qh1 = hp  + (size_t)(m0 + r1) * ODIM + c1 * 8;
  const unsigned short* sB0 = Bt + (size_t)(n0 + r0) * KDIM + c0 * 8;
  const unsigned short* sB1 = Bt + (size_t)(n0 + r1) * KDIM + c1 * 8;

  f32x4 acc[8][4] = {};

  // prologue: stage tiles 0,1,2 (A via f32 load+cvt+ds_write; B via gll)
#pragma unroll
  for (int t = 0; t < 3; ++t) {
    const int k = t * 32;
    const float* s0 = (k < 512) ? (qi0 + k) : (qh0 + (k - 512));
    const float* s1 = (k < 512) ? (qi1 + k) : (qh1 + (k - 512));
    float4 al0 = ((const float4*)s0)[0], al1 = ((const float4*)s0)[1];
    float4 ah0 = ((const float4*)s1)[0], ah1 = ((const float4*)s1)[1];
    *(u16x8*)(smem + t * BUFSZ + wl16)        = cvt8(al0, al1);
    *(u16x8*)(smem + t * BUFSZ + 8192 + wl16) = cvt8(ah0, ah1);
    gll16(sB0 + k, smem + t * BUFSZ + ABYTES + wave1024);
    gll16(sB1 + k, smem + t * BUFSZ + ABYTES + 8192 + wave1024);
  }
  VMW(0);
  LGKM0();
  BAR();
  sB0 += 96; sB1 += 96;   // B stage pointers -> tile 3
  int kstg = 96;          // A stage k -> tile 3

  // main loop: 32 K-tiles; tile t computes buf t&3, stages tile t+3
  for (int tt = 0; tt < 7; ++tt) {
    tile_body<0, true, false>(smem, qi0, qh0, qi1, qh1, sB0, sB1, kstg, wave1024, wl16, aoff, boff, acc);
    sB0 += 32; sB1 += 32; kstg += 32;
    tile_body<1, true, false>(smem, qi0, qh0, qi1, qh1, sB0, sB1, kstg, wave1024, wl16, aoff, boff, acc);
    sB0 += 32; sB1 += 32; kstg += 32;
    tile_body<2, true, false>(smem, qi0, qh0, qi1, qh1, sB0, sB1, kstg, wave1024, wl16, aoff, boff, acc);
    sB0 += 32; sB1 += 32; kstg += 32;
    tile_body<3, true, false>(smem, qi0, qh0, qi1, qh1, sB0, sB1, kstg, wave1024, wl16, aoff, boff, acc);
    sB0 += 32; sB1 += 32; kstg += 32;
  }
  tile_body<0, true,  false>(smem, qi0, qh0, qi1, qh1, sB0, sB1, kstg, wave1024, wl16, aoff, boff, acc);  // t28 stages t31
  tile_body<1, false, true >(smem, qi0, qh0, qi1, qh1, sB0, sB1, kstg, wave1024, wl16, aoff, boff, acc);  // t29: VMW(0) drains B(->31)
  tile_body<2, false, false>(smem, qi0, qh0, qi1, qh1, sB0, sB1, kstg, wave1024, wl16, aoff, boff, acc);  // t30
  tile_body<3, false, false>(smem, qi0, qh0, qi1, qh1, sB0, sB1, kstg, wave1024, wl16, aoff, boff, acc);  // t31

  // epilogue: C/D layout col = lane&15, row = (lane>>4)*4 + r
#pragma unroll
  for (int mi = 0; mi < 8; ++mi) {
#pragma unroll
    for (int ni = 0; ni < 4; ++ni) {
#pragma unroll
      for (int r = 0; r < 4; ++r) {
        const int row = m0 + wmR + mi * 16 + (lane >> 4) * 4 + r;
        const int col = n0 + wn + ni * 16 + lrow;
        Cz[(size_t)row * NDIM + col] = f2bf(acc[mi][ni][r]);
      }
    }
  }
  (void)wm;
}

// ---------------- LayerNorm + gates ----------------

__global__ __launch_bounds__(256) void ln_gate_kernel(const unsigned short* __restrict__ z,
                                                      const float* __restrict__ c,
                                                      const float* __restrict__ gamma,
                                                      const float* __restrict__ beta,
                                                      float* __restrict__ out) {
  __shared__ float rowbuf[4][NDIM];  // 32 KB
  const int wave = threadIdx.x >> 6;
  const int lane = threadIdx.x & 63;
  const int row = blockIdx.x * 4 + wave;
  const unsigned short* zr = z + (size_t)row * NDIM;

  float s = 0.f, ss = 0.f;
#pragma unroll
  for (int j = 0; j < 4; ++j) {
    const int chunk = j * 64 + lane;
    u16x8 v = *(const u16x8*)(zr + chunk * 8);
    float f[8];
#pragma unroll
    for (int i2 = 0; i2 < 8; ++i2) {
      f[i2] = bf2f(v[i2]);
      s += f[i2];
      ss += f[i2] * f[i2];
    }
    float4* dst = (float4*)&rowbuf[wave][chunk * 8];
    dst[0] = make_float4(f[0], f[1], f[2], f[3]);
    dst[1] = make_float4(f[4], f[5], f[6], f[7]);
  }
#pragma unroll
  for (int off = 32; off > 0; off >>= 1) {
    s += __shfl_xor(s, off, 64);
    ss += __shfl_xor(ss, off, 64);
  }
  const float mean = s * (1.f / (float)NDIM);
  const float var = ss * (1.f / (float)NDIM) - mean * mean;
  const float inv = rsqrtf(var + 1e-5f);

  float* out_o = out + (size_t)row * ODIM;
  float* out_c = out + (size_t)BDIM * ODIM + (size_t)row * ODIM;
  const float* crow = c + (size_t)row * ODIM;

#pragma unroll
  for (int j = 0; j < 8; ++j) {
    const int o = j * 64 + lane;
    float zn[4];
#pragma unroll
    for (int g = 0; g < 4; ++g) {
      float v = (rowbuf[wave][g * ODIM + o] - mean) * inv;
      zn[g] = v * gamma[g * ODIM + o] + beta[g * ODIM + o];
    }
    const float fg = 1.f / (1.f + expf(-zn[0]));
    const float ig = 1.f / (1.f + expf(-zn[1]));
    const float og = 1.f / (1.f + expf(-zn[2]));
    const float x = zn[3];
    const float hs = 0.5f * x * (1.f + erff(x * 0.70710678118654752f));
    const float cc = fg * crow[o] + ig * hs;
    out_c[o] = cc;
    out_o[o] = og * cc;
  }
}

// ---------------- launch ----------------

extern "C" void kernel_launch(void* const* d_in, const int* in_sizes, int n_in,
                              void* d_out, int out_size, void* d_ws, size_t ws_size,
                              hipStream_t stream) {
  const float* input = (const float*)d_in[0];
  const float* h     = (const float*)d_in[1];
  const float* c     = (const float*)d_in[2];
  const float* W     = (const float*)d_in[3];
  const float* gamma = (const float*)d_in[4];
  const float* beta  = (const float*)d_in[5];

  unsigned short* Wb = (unsigned short*)d_ws;                 // [2048,1024] bf16
  unsigned short* z  = Wb + (size_t)NDIM * KDIM;              // [32768,2048] bf16
  float* out = (float*)d_out;

  hipFuncSetAttribute((const void*)gemm_kernel,
                      hipFuncAttributeMaxDynamicSharedMemorySize, 131072);

  pack_w_kernel<<<(NDIM * KDIM / 8) / 256, 256, 0, stream>>>(W, Wb);
  gemm_kernel<<<dim3((BDIM / 256) * (NDIM / 256)), 512, 131072, stream>>>(input, h, Wb, z);
  ln_gate_kernel<<<BDIM / 4, 256, 0, stream>>>(z, c, gamma, beta, out);
}

// Round 12
// 256.395 us; speedup vs baseline: 1.2906x; 1.2906x over previous
//
#include <hip/hip_runtime.h>
#include <hip/hip_bf16.h>
#include <cstdint>
#include <cstddef>

#define BDIM 32768
#define IDIM 512
#define ODIM 512
#define KDIM 1024   // I+O
#define NDIM 2048   // 4*O

typedef __attribute__((ext_vector_type(8))) __bf16 bf16x8;
typedef __attribute__((ext_vector_type(4))) float f32x4;
typedef __attribute__((ext_vector_type(8))) unsigned short u16x8;

__device__ __forceinline__ unsigned short f2bf(float x) {
  union { float f; uint32_t u; } v; v.f = x;
  uint32_t r = v.u + 0x7FFFu + ((v.u >> 16) & 1u);  // RNE
  return (unsigned short)(r >> 16);
}

__device__ __forceinline__ float bf2f(unsigned short s) {
  union { uint32_t u; float f; } v; v.u = ((uint32_t)s) << 16;
  return v.f;
}

// ---------------- combined pack kernel: A ([input|h]) and W, f32 -> bf16 ----------------
// blocks [0, 16384): A (32768x1024); blocks [16384, 17408): W (2048x1024)

__global__ __launch_bounds__(256) void pack_ab_kernel(const float* __restrict__ in,
                                                      const float* __restrict__ h,
                                                      const float* __restrict__ Wsrc,
                                                      unsigned short* __restrict__ A,
                                                      unsigned short* __restrict__ Wb) {
  const int b = blockIdx.x;
  if (b < 16384) {
    size_t t = (size_t)b * 256 + threadIdx.x;
    size_t e = t * 8;
    size_t row = e >> 10;
    int col = (int)(e & 1023);
    const float* src = (col < IDIM) ? (in + row * IDIM + col)
                                    : (h + row * ODIM + (col - IDIM));
    float4 v0 = ((const float4*)src)[0];
    float4 v1 = ((const float4*)src)[1];
    u16x8 r;
    r[0] = f2bf(v0.x); r[1] = f2bf(v0.y); r[2] = f2bf(v0.z); r[3] = f2bf(v0.w);
    r[4] = f2bf(v1.x); r[5] = f2bf(v1.y); r[6] = f2bf(v1.z); r[7] = f2bf(v1.w);
    *(u16x8*)(A + e) = r;
  } else {
    size_t t = (size_t)(b - 16384) * 256 + threadIdx.x;
    size_t e = t * 8;
    float4 v0 = ((const float4*)(Wsrc + e))[0];
    float4 v1 = ((const float4*)(Wsrc + e))[1];
    u16x8 r;
    r[0] = f2bf(v0.x); r[1] = f2bf(v0.y); r[2] = f2bf(v0.z); r[3] = f2bf(v0.w);
    r[4] = f2bf(v1.x); r[5] = f2bf(v1.y); r[6] = f2bf(v1.z); r[7] = f2bf(v1.w);
    *(u16x8*)(Wb + e) = r;
  }
}

// ---------------- GEMM: R3 champion verbatim (904 TF = m97-structure ceiling) ----------------
// 256x256 tile, BK=32, ring-4 LDS (128KB), 8 waves (2M x 4N), XOR-chunk swizzle,
// counted vmcnt(8), 2 phases/K-tile, XCD-aware block swizzle.

#define BUFSZ 32768
#define ABYTES 16384

#define BAR() do { asm volatile("" ::: "memory"); __builtin_amdgcn_s_barrier(); asm volatile("" ::: "memory"); } while (0)
#define VMW(n) asm volatile("s_waitcnt vmcnt(" #n ")" ::: "memory")

__device__ __forceinline__ void gll16(const unsigned short* src, char* ldsdst) {
  __builtin_amdgcn_global_load_lds(
      (const __attribute__((address_space(1))) void*)src,
      (__attribute__((address_space(3))) void*)ldsdst, 16, 0, 0);
}

template<int BUF, int VM, bool STG, int TO>
__device__ __forceinline__ void tile_body(char* smem,
                                          const unsigned short* sA0, const unsigned short* sA1,
                                          const unsigned short* sB0, const unsigned short* sB1,
                                          int wave1024, int aoff, int boff,
                                          f32x4 (&acc)[8][4]) {
  char* const Ab = smem + BUF * BUFSZ;
  char* const Bb = Ab + ABYTES;
  constexpr int DB = ((BUF + 3) & 3) * BUFSZ;

  if (VM == 8)      VMW(8);
  else if (VM == 4) VMW(4);
  else              VMW(0);
  BAR();

  // ---- phase 0: A frags 0-3 + all B frags; stage part 0 of tile BUF+3 ----
  bf16x8 x0 = *(const bf16x8*)(Ab + aoff + 0 * 1024);
  bf16x8 x1 = *(const bf16x8*)(Ab + aoff + 1 * 1024);
  bf16x8 x2 = *(const bf16x8*)(Ab + aoff + 2 * 1024);
  bf16x8 x3 = *(const bf16x8*)(Ab + aoff + 3 * 1024);
  bf16x8 b0 = *(const bf16x8*)(Bb + boff + 0 * 1024);
  bf16x8 b1 = *(const bf16x8*)(Bb + boff + 1 * 1024);
  bf16x8 b2 = *(const bf16x8*)(Bb + boff + 2 * 1024);
  bf16x8 b3 = *(const bf16x8*)(Bb + boff + 3 * 1024);
  if (STG) {
    gll16(sA0 + TO * 32, smem + DB + wave1024);
    gll16(sB0 + TO * 32, smem + DB + ABYTES + wave1024);
  }
  BAR();
  __builtin_amdgcn_sched_barrier(0);
  __builtin_amdgcn_s_setprio(1);
  acc[0][0] = __builtin_amdgcn_mfma_f32_16x16x32_bf16(x0, b0, acc[0][0], 0, 0, 0);
  acc[0][1] = __builtin_amdgcn_mfma_f32_16x16x32_bf16(x0, b1, acc[0][1], 0, 0, 0);
  acc[0][2] = __builtin_amdgcn_mfma_f32_16x16x32_bf16(x0, b2, acc[0][2], 0, 0, 0);
  acc[0][3] = __builtin_amdgcn_mfma_f32_16x16x32_bf16(x0, b3, acc[0][3], 0, 0, 0);
  acc[1][0] = __builtin_amdgcn_mfma_f32_16x16x32_bf16(x1, b0, acc[1][0], 0, 0, 0);
  acc[1][1] = __builtin_amdgcn_mfma_f32_16x16x32_bf16(x1, b1, acc[1][1], 0, 0, 0);
  acc[1][2] = __builtin_amdgcn_mfma_f32_16x16x32_bf16(x1, b2, acc[1][2], 0, 0, 0);
  acc[1][3] = __builtin_amdgcn_mfma_f32_16x16x32_bf16(x1, b3, acc[1][3], 0, 0, 0);
  acc[2][0] = __builtin_amdgcn_mfma_f32_16x16x32_bf16(x2, b0, acc[2][0], 0, 0, 0);
  acc[2][1] = __builtin_amdgcn_mfma_f32_16x16x32_bf16(x2, b1, acc[2][1], 0, 0, 0);
  acc[2][2] = __builtin_amdgcn_mfma_f32_16x16x32_bf16(x2, b2, acc[2][2], 0, 0, 0);
  acc[2][3] = __builtin_amdgcn_mfma_f32_16x16x32_bf16(x2, b3, acc[2][3], 0, 0, 0);
  acc[3][0] = __builtin_amdgcn_mfma_f32_16x16x32_bf16(x3, b0, acc[3][0], 0, 0, 0);
  acc[3][1] = __builtin_amdgcn_mfma_f32_16x16x32_bf16(x3, b1, acc[3][1], 0, 0, 0);
  acc[3][2] = __builtin_amdgcn_mfma_f32_16x16x32_bf16(x3, b2, acc[3][2], 0, 0, 0);
  acc[3][3] = __builtin_amdgcn_mfma_f32_16x16x32_bf16(x3, b3, acc[3][3], 0, 0, 0);
  __builtin_amdgcn_s_setprio(0);
  __builtin_amdgcn_sched_barrier(0);
  BAR();

  // ---- phase 1: A frags 4-7; stage part 1 of tile BUF+3 ----
  x0 = *(const bf16x8*)(Ab + aoff + 4 * 1024);
  x1 = *(const bf16x8*)(Ab + aoff + 5 * 1024);
  x2 = *(const bf16x8*)(Ab + aoff + 6 * 1024);
  x3 = *(const bf16x8*)(Ab + aoff + 7 * 1024);
  if (STG) {
    gll16(sA1 + TO * 32, smem + DB + 8192 + wave1024);
    gll16(sB1 + TO * 32, smem + DB + ABYTES + 8192 + wave1024);
  }
  BAR();
  __builtin_amdgcn_sched_barrier(0);
  __builtin_amdgcn_s_setprio(1);
  acc[4][0] = __builtin_amdgcn_mfma_f32_16x16x32_bf16(x0, b0, acc[4][0], 0, 0, 0);
  acc[4][1] = __builtin_amdgcn_mfma_f32_16x16x32_bf16(x0, b1, acc[4][1], 0, 0, 0);
  acc[4][2] = __builtin_amdgcn_mfma_f32_16x16x32_bf16(x0, b2, acc[4][2], 0, 0, 0);
  acc[4][3] = __builtin_amdgcn_mfma_f32_16x16x32_bf16(x0, b3, acc[4][3], 0, 0, 0);
  acc[5][0] = __builtin_amdgcn_mfma_f32_16x16x32_bf16(x1, b0, acc[5][0], 0, 0, 0);
  acc[5][1] = __builtin_amdgcn_mfma_f32_16x16x32_bf16(x1, b1, acc[5][1], 0, 0, 0);
  acc[5][2] = __builtin_amdgcn_mfma_f32_16x16x32_bf16(x1, b2, acc[5][2], 0, 0, 0);
  acc[5][3] = __builtin_amdgcn_mfma_f32_16x16x32_bf16(x1, b3, acc[5][3], 0, 0, 0);
  acc[6][0] = __builtin_amdgcn_mfma_f32_16x16x32_bf16(x2, b0, acc[6][0], 0, 0, 0);
  acc[6][1] = __builtin_amdgcn_mfma_f32_16x16x32_bf16(x2, b1, acc[6][1], 0, 0, 0);
  acc[6][2] = __builtin_amdgcn_mfma_f32_16x16x32_bf16(x2, b2, acc[6][2], 0, 0, 0);
  acc[6][3] = __builtin_amdgcn_mfma_f32_16x16x32_bf16(x2, b3, acc[6][3], 0, 0, 0);
  acc[7][0] = __builtin_amdgcn_mfma_f32_16x16x32_bf16(x3, b0, acc[7][0], 0, 0, 0);
  acc[7][1] = __builtin_amdgcn_mfma_f32_16x16x32_bf16(x3, b1, acc[7][1], 0, 0, 0);
  acc[7][2] = __builtin_amdgcn_mfma_f32_16x16x32_bf16(x3, b2, acc[7][2], 0, 0, 0);
  acc[7][3] = __builtin_amdgcn_mfma_f32_16x16x32_bf16(x3, b3, acc[7][3], 0, 0, 0);
  __builtin_amdgcn_s_setprio(0);
  __builtin_amdgcn_sched_barrier(0);
  // no trailing barrier: next tile's top barrier covers it
}

__global__ __launch_bounds__(512, 2) void gemm_kernel(const unsigned short* __restrict__ A,
                                                      const unsigned short* __restrict__ Bt,
                                                      unsigned short* __restrict__ Cz) {
  extern __shared__ char smem[];
  const int tid = threadIdx.x;
  const int wave = tid >> 6;
  const int lane = tid & 63;

  // XCD swizzle: each XCD gets a 16-mtile x 8-ntile chunk (B panel L2-resident)
  const int bid = blockIdx.x;                       // 0..1023
  const int swz = (bid & 7) * 128 + (bid >> 3);
  const int m0 = (swz >> 3) * 256;
  const int n0 = (swz & 7) * 256;

  const int wm = (wave >> 2) * 128;   // 2 M-wave-rows
  const int wn = (wave & 3) * 64;     // 4 N-wave-cols
  const int lrow = lane & 15;
  const int cswz16 = (((lane >> 4) ^ (lrow >> 2)) & 3) * 16;
  const int aoff = (wm + lrow) * 64 + cswz16;
  const int boff = (wn + lrow) * 64 + cswz16;
  const int wave1024 = wave * 1024;

  // staging source pointers (pre-swizzled global addresses)
  const int r0 = tid >> 2;
  const int r1 = r0 + 128;
  const int c0 = (tid & 3) ^ ((r0 >> 2) & 3);
  const int c1 = (tid & 3) ^ ((r1 >> 2) & 3);
  const unsigned short* sA0 = A  + (size_t)(m0 + r0) * KDIM + c0 * 8;
  const unsigned short* sA1 = A  + (size_t)(m0 + r1) * KDIM + c1 * 8;
  const unsigned short* sB0 = Bt + (size_t)(n0 + r0) * KDIM + c0 * 8;
  const unsigned short* sB1 = Bt + (size_t)(n0 + r1) * KDIM + c1 * 8;

  f32x4 acc[8][4] = {};

  // prologue: stage tiles 0,1,2 (12 loads/thread, grouped by tile for vmcnt FIFO)
  gll16(sA0,      smem + 0 * BUFSZ + wave1024);
  gll16(sB0,      smem + 0 * BUFSZ + ABYTES + wave1024);
  gll16(sA1,      smem + 0 * BUFSZ + 8192 + wave1024);
  gll16(sB1,      smem + 0 * BUFSZ + ABYTES + 8192 + wave1024);
  gll16(sA0 + 32, smem + 1 * BUFSZ + wave1024);
  gll16(sB0 + 32, smem + 1 * BUFSZ + ABYTES + wave1024);
  gll16(sA1 + 32, smem + 1 * BUFSZ + 8192 + wave1024);
  gll16(sB1 + 32, smem + 1 * BUFSZ + ABYTES + 8192 + wave1024);
  gll16(sA0 + 64, smem + 2 * BUFSZ + wave1024);
  gll16(sB0 + 64, smem + 2 * BUFSZ + ABYTES + wave1024);
  gll16(sA1 + 64, smem + 2 * BUFSZ + 8192 + wave1024);
  gll16(sB1 + 64, smem + 2 * BUFSZ + ABYTES + 8192 + wave1024);

  // main loop: tiles 0..27 (stage tiles 3..30)
  for (int t4 = 0; t4 < 28; t4 += 4) {
    tile_body<0, 8, true, 3>(smem, sA0, sA1, sB0, sB1, wave1024, aoff, boff, acc);
    tile_body<1, 8, true, 4>(smem, sA0, sA1, sB0, sB1, wave1024, aoff, boff, acc);
    tile_body<2, 8, true, 5>(smem, sA0, sA1, sB0, sB1, wave1024, aoff, boff, acc);
    tile_body<3, 8, true, 6>(smem, sA0, sA1, sB0, sB1, wave1024, aoff, boff, acc);
    sA0 += 128; sA1 += 128; sB0 += 128; sB1 += 128;
  }
  // tiles 28..31 (tile 28 stages tile 31; then taper vmcnt 8 -> 4 -> 0)
  tile_body<0, 8, true,  3>(smem, sA0, sA1, sB0, sB1, wave1024, aoff, boff, acc);
  tile_body<1, 8, false, 0>(smem, sA0, sA1, sB0, sB1, wave1024, aoff, boff, acc);
  tile_body<2, 4, false, 0>(smem, sA0, sA1, sB0, sB1, wave1024, aoff, boff, acc);
  tile_body<3, 0, false, 0>(smem, sA0, sA1, sB0, sB1, wave1024, aoff, boff, acc);

  // epilogue: C/D layout col = lane&15, row = (lane>>4)*4 + r
#pragma unroll
  for (int mi = 0; mi < 8; ++mi) {
#pragma unroll
    for (int ni = 0; ni < 4; ++ni) {
#pragma unroll
      for (int r = 0; r < 4; ++r) {
        const int row = m0 + wm + mi * 16 + (lane >> 4) * 4 + r;
        const int col = n0 + wn + ni * 16 + lrow;
        Cz[(size_t)row * NDIM + col] = f2bf(acc[mi][ni][r]);
      }
    }
  }
}

// ---------------- LayerNorm + gates (bf16 LDS rowbuf, 16KB/block) ----------------

__global__ __launch_bounds__(256) void ln_gate_kernel(const unsigned short* __restrict__ z,
                                                      const float* __restrict__ c,
                                                      const float* __restrict__ gamma,
                                                      const float* __restrict__ beta,
                                                      float* __restrict__ out) {
  __shared__ unsigned short rowbuf[4][NDIM];  // 16 KB (raw bf16)
  const int wave = threadIdx.x >> 6;
  const int lane = threadIdx.x & 63;
  const int row = blockIdx.x * 4 + wave;
  const unsigned short* zr = z + (size_t)row * NDIM;

  float s = 0.f, ss = 0.f;
#pragma unroll
  for (int j = 0; j < 4; ++j) {
    const int chunk = j * 64 + lane;
    u16x8 v = *(const u16x8*)(zr + chunk * 8);
    *(u16x8*)&rowbuf[wave][chunk * 8] = v;   // raw bf16 store
#pragma unroll
    for (int i2 = 0; i2 < 8; ++i2) {
      float f = bf2f(v[i2]);
      s += f;
      ss += f * f;
    }
  }
#pragma unroll
  for (int off = 32; off > 0; off >>= 1) {
    s += __shfl_xor(s, off, 64);
    ss += __shfl_xor(ss, off, 64);
  }
  const float mean = s * (1.f / (float)NDIM);
  const float var = ss * (1.f / (float)NDIM) - mean * mean;
  const float inv = rsqrtf(var + 1e-5f);

  float* out_o = out + (size_t)row * ODIM;
  float* out_c = out + (size_t)BDIM * ODIM + (size_t)row * ODIM;
  const float* crow = c + (size_t)row * ODIM;

#pragma unroll
  for (int j = 0; j < 8; ++j) {
    const int o = j * 64 + lane;
    float zn[4];
#pragma unroll
    for (int g = 0; g < 4; ++g) {
      float v = (bf2f(rowbuf[wave][g * ODIM + o]) - mean) * inv;
      zn[g] = v * gamma[g * ODIM + o] + beta[g * ODIM + o];
    }
    const float fg = 1.f / (1.f + expf(-zn[0]));
    const float ig = 1.f / (1.f + expf(-zn[1]));
    const float og = 1.f / (1.f + expf(-zn[2]));
    const float x = zn[3];
    const float hs = 0.5f * x * (1.f + erff(x * 0.70710678118654752f));
    const float cc = fg * crow[o] + ig * hs;
    out_c[o] = cc;
    out_o[o] = og * cc;
  }
}

// ---------------- launch ----------------

extern "C" void kernel_launch(void* const* d_in, const int* in_sizes, int n_in,
                              void* d_out, int out_size, void* d_ws, size_t ws_size,
                              hipStream_t stream) {
  const float* input = (const float*)d_in[0];
  const float* h     = (const float*)d_in[1];
  const float* c     = (const float*)d_in[2];
  const float* W     = (const float*)d_in[3];
  const float* gamma = (const float*)d_in[4];
  const float* beta  = (const float*)d_in[5];

  unsigned short* A  = (unsigned short*)d_ws;                 // [32768,1024] bf16
  unsigned short* Wb = A + (size_t)BDIM * KDIM;               // [2048,1024] bf16
  unsigned short* z  = Wb + (size_t)NDIM * KDIM;              // [32768,2048] bf16
  float* out = (float*)d_out;

  hipFuncSetAttribute((const void*)gemm_kernel,
                      hipFuncAttributeMaxDynamicSharedMemorySize, 131072);

  pack_ab_kernel<<<16384 + 1024, 256, 0, stream>>>(input, h, W, A, Wb);
  gemm_kernel<<<dim3((BDIM / 256) * (NDIM / 256)), 512, 131072, stream>>>(A, Wb, z);
  ln_gate_kernel<<<BDIM / 4, 256, 0, stream>>>(z, c, gamma, beta, out);
}

// Round 13
// 242.765 us; speedup vs baseline: 1.3630x; 1.0561x over previous
//
#include <hip/hip_runtime.h>
#include <hip/hip_bf16.h>
#include <cstdint>
#include <cstddef>

#define BDIM 32768
#define IDIM 512
#define ODIM 512
#define KDIM 1024   // I+O
#define NDIM 2048   // 4*O

typedef __attribute__((ext_vector_type(8))) __bf16 bf16x8;
typedef __attribute__((ext_vector_type(4))) float f32x4;
typedef __attribute__((ext_vector_type(8))) unsigned short u16x8;

__device__ __forceinline__ unsigned short f2bf(float x) {
  union { float f; uint32_t u; } v; v.f = x;
  uint32_t r = v.u + 0x7FFFu + ((v.u >> 16) & 1u);  // RNE
  return (unsigned short)(r >> 16);
}

__device__ __forceinline__ float bf2f(unsigned short s) {
  union { uint32_t u; float f; } v; v.u = ((uint32_t)s) << 16;
  return v.f;
}

// ---------------- combined pack kernel: A ([input|h]) and W, f32 -> bf16 ----------------
// blocks [0, 16384): A (32768x1024); blocks [16384, 17408): W (2048x1024)

__global__ __launch_bounds__(256) void pack_ab_kernel(const float* __restrict__ in,
                                                      const float* __restrict__ h,
                                                      const float* __restrict__ Wsrc,
                                                      unsigned short* __restrict__ A,
                                                      unsigned short* __restrict__ Wb) {
  const int b = blockIdx.x;
  if (b < 16384) {
    size_t t = (size_t)b * 256 + threadIdx.x;
    size_t e = t * 8;
    size_t row = e >> 10;
    int col = (int)(e & 1023);
    const float* src = (col < IDIM) ? (in + row * IDIM + col)
                                    : (h + row * ODIM + (col - IDIM));
    float4 v0 = ((const float4*)src)[0];
    float4 v1 = ((const float4*)src)[1];
    u16x8 r;
    r[0] = f2bf(v0.x); r[1] = f2bf(v0.y); r[2] = f2bf(v0.z); r[3] = f2bf(v0.w);
    r[4] = f2bf(v1.x); r[5] = f2bf(v1.y); r[6] = f2bf(v1.z); r[7] = f2bf(v1.w);
    *(u16x8*)(A + e) = r;
  } else {
    size_t t = (size_t)(b - 16384) * 256 + threadIdx.x;
    size_t e = t * 8;
    float4 v0 = ((const float4*)(Wsrc + e))[0];
    float4 v1 = ((const float4*)(Wsrc + e))[1];
    u16x8 r;
    r[0] = f2bf(v0.x); r[1] = f2bf(v0.y); r[2] = f2bf(v0.z); r[3] = f2bf(v0.w);
    r[4] = f2bf(v1.x); r[5] = f2bf(v1.y); r[6] = f2bf(v1.z); r[7] = f2bf(v1.w);
    *(u16x8*)(Wb + e) = r;
  }
}

// ---------------- GEMM: R3 champion verbatim (904 TF = m97-structure ceiling) ----------------
// 256x256 tile, BK=32, ring-4 LDS (128KB), 8 waves (2M x 4N), XOR-chunk swizzle,
// counted vmcnt(8), 2 phases/K-tile, XCD-aware block swizzle. DO NOT TOUCH:
// six structurally-distinct rewrites (R4-R11) all landed at or below this.

#define BUFSZ 32768
#define ABYTES 16384

#define BAR() do { asm volatile("" ::: "memory"); __builtin_amdgcn_s_barrier(); asm volatile("" ::: "memory"); } while (0)
#define VMW(n) asm volatile("s_waitcnt vmcnt(" #n ")" ::: "memory")

__device__ __forceinline__ void gll16(const unsigned short* src, char* ldsdst) {
  __builtin_amdgcn_global_load_lds(
      (const __attribute__((address_space(1))) void*)src,
      (__attribute__((address_space(3))) void*)ldsdst, 16, 0, 0);
}

template<int BUF, int VM, bool STG, int TO>
__device__ __forceinline__ void tile_body(char* smem,
                                          const unsigned short* sA0, const unsigned short* sA1,
                                          const unsigned short* sB0, const unsigned short* sB1,
                                          int wave1024, int aoff, int boff,
                                          f32x4 (&acc)[8][4]) {
  char* const Ab = smem + BUF * BUFSZ;
  char* const Bb = Ab + ABYTES;
  constexpr int DB = ((BUF + 3) & 3) * BUFSZ;

  if (VM == 8)      VMW(8);
  else if (VM == 4) VMW(4);
  else              VMW(0);
  BAR();

  // ---- phase 0: A frags 0-3 + all B frags; stage part 0 of tile BUF+3 ----
  bf16x8 x0 = *(const bf16x8*)(Ab + aoff + 0 * 1024);
  bf16x8 x1 = *(const bf16x8*)(Ab + aoff + 1 * 1024);
  bf16x8 x2 = *(const bf16x8*)(Ab + aoff + 2 * 1024);
  bf16x8 x3 = *(const bf16x8*)(Ab + aoff + 3 * 1024);
  bf16x8 b0 = *(const bf16x8*)(Bb + boff + 0 * 1024);
  bf16x8 b1 = *(const bf16x8*)(Bb + boff + 1 * 1024);
  bf16x8 b2 = *(const bf16x8*)(Bb + boff + 2 * 1024);
  bf16x8 b3 = *(const bf16x8*)(Bb + boff + 3 * 1024);
  if (STG) {
    gll16(sA0 + TO * 32, smem + DB + wave1024);
    gll16(sB0 + TO * 32, smem + DB + ABYTES + wave1024);
  }
  BAR();
  __builtin_amdgcn_sched_barrier(0);
  __builtin_amdgcn_s_setprio(1);
  acc[0][0] = __builtin_amdgcn_mfma_f32_16x16x32_bf16(x0, b0, acc[0][0], 0, 0, 0);
  acc[0][1] = __builtin_amdgcn_mfma_f32_16x16x32_bf16(x0, b1, acc[0][1], 0, 0, 0);
  acc[0][2] = __builtin_amdgcn_mfma_f32_16x16x32_bf16(x0, b2, acc[0][2], 0, 0, 0);
  acc[0][3] = __builtin_amdgcn_mfma_f32_16x16x32_bf16(x0, b3, acc[0][3], 0, 0, 0);
  acc[1][0] = __builtin_amdgcn_mfma_f32_16x16x32_bf16(x1, b0, acc[1][0], 0, 0, 0);
  acc[1][1] = __builtin_amdgcn_mfma_f32_16x16x32_bf16(x1, b1, acc[1][1], 0, 0, 0);
  acc[1][2] = __builtin_amdgcn_mfma_f32_16x16x32_bf16(x1, b2, acc[1][2], 0, 0, 0);
  acc[1][3] = __builtin_amdgcn_mfma_f32_16x16x32_bf16(x1, b3, acc[1][3], 0, 0, 0);
  acc[2][0] = __builtin_amdgcn_mfma_f32_16x16x32_bf16(x2, b0, acc[2][0], 0, 0, 0);
  acc[2][1] = __builtin_amdgcn_mfma_f32_16x16x32_bf16(x2, b1, acc[2][1], 0, 0, 0);
  acc[2][2] = __builtin_amdgcn_mfma_f32_16x16x32_bf16(x2, b2, acc[2][2], 0, 0, 0);
  acc[2][3] = __builtin_amdgcn_mfma_f32_16x16x32_bf16(x2, b3, acc[2][3], 0, 0, 0);
  acc[3][0] = __builtin_amdgcn_mfma_f32_16x16x32_bf16(x3, b0, acc[3][0], 0, 0, 0);
  acc[3][1] = __builtin_amdgcn_mfma_f32_16x16x32_bf16(x3, b1, acc[3][1], 0, 0, 0);
  acc[3][2] = __builtin_amdgcn_mfma_f32_16x16x32_bf16(x3, b2, acc[3][2], 0, 0, 0);
  acc[3][3] = __builtin_amdgcn_mfma_f32_16x16x32_bf16(x3, b3, acc[3][3], 0, 0, 0);
  __builtin_amdgcn_s_setprio(0);
  __builtin_amdgcn_sched_barrier(0);
  BAR();

  // ---- phase 1: A frags 4-7; stage part 1 of tile BUF+3 ----
  x0 = *(const bf16x8*)(Ab + aoff + 4 * 1024);
  x1 = *(const bf16x8*)(Ab + aoff + 5 * 1024);
  x2 = *(const bf16x8*)(Ab + aoff + 6 * 1024);
  x3 = *(const bf16x8*)(Ab + aoff + 7 * 1024);
  if (STG) {
    gll16(sA1 + TO * 32, smem + DB + 8192 + wave1024);
    gll16(sB1 + TO * 32, smem + DB + ABYTES + 8192 + wave1024);
  }
  BAR();
  __builtin_amdgcn_sched_barrier(0);
  __builtin_amdgcn_s_setprio(1);
  acc[4][0] = __builtin_amdgcn_mfma_f32_16x16x32_bf16(x0, b0, acc[4][0], 0, 0, 0);
  acc[4][1] = __builtin_amdgcn_mfma_f32_16x16x32_bf16(x0, b1, acc[4][1], 0, 0, 0);
  acc[4][2] = __builtin_amdgcn_mfma_f32_16x16x32_bf16(x0, b2, acc[4][2], 0, 0, 0);
  acc[4][3] = __builtin_amdgcn_mfma_f32_16x16x32_bf16(x0, b3, acc[4][3], 0, 0, 0);
  acc[5][0] = __builtin_amdgcn_mfma_f32_16x16x32_bf16(x1, b0, acc[5][0], 0, 0, 0);
  acc[5][1] = __builtin_amdgcn_mfma_f32_16x16x32_bf16(x1, b1, acc[5][1], 0, 0, 0);
  acc[5][2] = __builtin_amdgcn_mfma_f32_16x16x32_bf16(x1, b2, acc[5][2], 0, 0, 0);
  acc[5][3] = __builtin_amdgcn_mfma_f32_16x16x32_bf16(x1, b3, acc[5][3], 0, 0, 0);
  acc[6][0] = __builtin_amdgcn_mfma_f32_16x16x32_bf16(x2, b0, acc[6][0], 0, 0, 0);
  acc[6][1] = __builtin_amdgcn_mfma_f32_16x16x32_bf16(x2, b1, acc[6][1], 0, 0, 0);
  acc[6][2] = __builtin_amdgcn_mfma_f32_16x16x32_bf16(x2, b2, acc[6][2], 0, 0, 0);
  acc[6][3] = __builtin_amdgcn_mfma_f32_16x16x32_bf16(x2, b3, acc[6][3], 0, 0, 0);
  acc[7][0] = __builtin_amdgcn_mfma_f32_16x16x32_bf16(x3, b0, acc[7][0], 0, 0, 0);
  acc[7][1] = __builtin_amdgcn_mfma_f32_16x16x32_bf16(x3, b1, acc[7][1], 0, 0, 0);
  acc[7][2] = __builtin_amdgcn_mfma_f32_16x16x32_bf16(x3, b2, acc[7][2], 0, 0, 0);
  acc[7][3] = __builtin_amdgcn_mfma_f32_16x16x32_bf16(x3, b3, acc[7][3], 0, 0, 0);
  __builtin_amdgcn_s_setprio(0);
  __builtin_amdgcn_sched_barrier(0);
  // no trailing barrier: next tile's top barrier covers it
}

__global__ __launch_bounds__(512, 2) void gemm_kernel(const unsigned short* __restrict__ A,
                                                      const unsigned short* __restrict__ Bt,
                                                      unsigned short* __restrict__ Cz) {
  extern __shared__ char smem[];
  const int tid = threadIdx.x;
  const int wave = tid >> 6;
  const int lane = tid & 63;

  // XCD swizzle: each XCD gets a 16-mtile x 8-ntile chunk (B panel L2-resident)
  const int bid = blockIdx.x;                       // 0..1023
  const int swz = (bid & 7) * 128 + (bid >> 3);
  const int m0 = (swz >> 3) * 256;
  const int n0 = (swz & 7) * 256;

  const int wm = (wave >> 2) * 128;   // 2 M-wave-rows
  const int wn = (wave & 3) * 64;     // 4 N-wave-cols
  const int lrow = lane & 15;
  const int cswz16 = (((lane >> 4) ^ (lrow >> 2)) & 3) * 16;
  const int aoff = (wm + lrow) * 64 + cswz16;
  const int boff = (wn + lrow) * 64 + cswz16;
  const int wave1024 = wave * 1024;

  // staging source pointers (pre-swizzled global addresses)
  const int r0 = tid >> 2;
  const int r1 = r0 + 128;
  const int c0 = (tid & 3) ^ ((r0 >> 2) & 3);
  const int c1 = (tid & 3) ^ ((r1 >> 2) & 3);
  const unsigned short* sA0 = A  + (size_t)(m0 + r0) * KDIM + c0 * 8;
  const unsigned short* sA1 = A  + (size_t)(m0 + r1) * KDIM + c1 * 8;
  const unsigned short* sB0 = Bt + (size_t)(n0 + r0) * KDIM + c0 * 8;
  const unsigned short* sB1 = Bt + (size_t)(n0 + r1) * KDIM + c1 * 8;

  f32x4 acc[8][4] = {};

  // prologue: stage tiles 0,1,2 (12 loads/thread, grouped by tile for vmcnt FIFO)
  gll16(sA0,      smem + 0 * BUFSZ + wave1024);
  gll16(sB0,      smem + 0 * BUFSZ + ABYTES + wave1024);
  gll16(sA1,      smem + 0 * BUFSZ + 8192 + wave1024);
  gll16(sB1,      smem + 0 * BUFSZ + ABYTES + 8192 + wave1024);
  gll16(sA0 + 32, smem + 1 * BUFSZ + wave1024);
  gll16(sB0 + 32, smem + 1 * BUFSZ + ABYTES + wave1024);
  gll16(sA1 + 32, smem + 1 * BUFSZ + 8192 + wave1024);
  gll16(sB1 + 32, smem + 1 * BUFSZ + ABYTES + 8192 + wave1024);
  gll16(sA0 + 64, smem + 2 * BUFSZ + wave1024);
  gll16(sB0 + 64, smem + 2 * BUFSZ + ABYTES + wave1024);
  gll16(sA1 + 64, smem + 2 * BUFSZ + 8192 + wave1024);
  gll16(sB1 + 64, smem + 2 * BUFSZ + ABYTES + 8192 + wave1024);

  // main loop: tiles 0..27 (stage tiles 3..30)
  for (int t4 = 0; t4 < 28; t4 += 4) {
    tile_body<0, 8, true, 3>(smem, sA0, sA1, sB0, sB1, wave1024, aoff, boff, acc);
    tile_body<1, 8, true, 4>(smem, sA0, sA1, sB0, sB1, wave1024, aoff, boff, acc);
    tile_body<2, 8, true, 5>(smem, sA0, sA1, sB0, sB1, wave1024, aoff, boff, acc);
    tile_body<3, 8, true, 6>(smem, sA0, sA1, sB0, sB1, wave1024, aoff, boff, acc);
    sA0 += 128; sA1 += 128; sB0 += 128; sB1 += 128;
  }
  // tiles 28..31 (tile 28 stages tile 31; then taper vmcnt 8 -> 4 -> 0)
  tile_body<0, 8, true,  3>(smem, sA0, sA1, sB0, sB1, wave1024, aoff, boff, acc);
  tile_body<1, 8, false, 0>(smem, sA0, sA1, sB0, sB1, wave1024, aoff, boff, acc);
  tile_body<2, 4, false, 0>(smem, sA0, sA1, sB0, sB1, wave1024, aoff, boff, acc);
  tile_body<3, 0, false, 0>(smem, sA0, sA1, sB0, sB1, wave1024, aoff, boff, acc);

  // epilogue: C/D layout col = lane&15, row = (lane>>4)*4 + r
#pragma unroll
  for (int mi = 0; mi < 8; ++mi) {
#pragma unroll
    for (int ni = 0; ni < 4; ++ni) {
#pragma unroll
      for (int r = 0; r < 4; ++r) {
        const int row = m0 + wm + mi * 16 + (lane >> 4) * 4 + r;
        const int col = n0 + wn + ni * 16 + lrow;
        Cz[(size_t)row * NDIM + col] = f2bf(acc[mi][ni][r]);
      }
    }
  }
}

// ---------------- LayerNorm + gates (bf16 LDS rowbuf, c-prefetch, nt streaming) ----------------
// 512 threads = 8 waves, one row per wave, 8 rows/block, 4096 blocks.
// c-row loads hoisted BEFORE the shuffle reduce (latency hides under it).
// z/c loads and out stores are nontemporal (read-once / write-once streams).

__global__ __launch_bounds__(512) void ln_gate_kernel(const unsigned short* __restrict__ z,
                                                      const float* __restrict__ c,
                                                      const float* __restrict__ gamma,
                                                      const float* __restrict__ beta,
                                                      float* __restrict__ out) {
  __shared__ unsigned short rowbuf[8][NDIM];  // 32 KB (raw bf16)
  const int wave = threadIdx.x >> 6;
  const int lane = threadIdx.x & 63;
  const int row = blockIdx.x * 8 + wave;
  const unsigned short* zr = z + (size_t)row * NDIM;
  const float* crow = c + (size_t)row * ODIM;

  // issue c-row loads early (consumed after the reduce)
  float cr[8];
#pragma unroll
  for (int j = 0; j < 8; ++j)
    cr[j] = __builtin_nontemporal_load(crow + j * 64 + lane);

  float s = 0.f, ss = 0.f;
#pragma unroll
  for (int j = 0; j < 4; ++j) {
    const int chunk = j * 64 + lane;
    u16x8 v = __builtin_nontemporal_load((const u16x8*)(zr + chunk * 8));
    *(u16x8*)&rowbuf[wave][chunk * 8] = v;   // raw bf16 store
#pragma unroll
    for (int i2 = 0; i2 < 8; ++i2) {
      float f = bf2f(v[i2]);
      s += f;
      ss += f * f;
    }
  }
#pragma unroll
  for (int off = 32; off > 0; off >>= 1) {
    s += __shfl_xor(s, off, 64);
    ss += __shfl_xor(ss, off, 64);
  }
  const float mean = s * (1.f / (float)NDIM);
  const float var = ss * (1.f / (float)NDIM) - mean * mean;
  const float inv = rsqrtf(var + 1e-5f);

  float* out_o = out + (size_t)row * ODIM;
  float* out_c = out + (size_t)BDIM * ODIM + (size_t)row * ODIM;

#pragma unroll
  for (int j = 0; j < 8; ++j) {
    const int o = j * 64 + lane;
    float zn[4];
#pragma unroll
    for (int g = 0; g < 4; ++g) {
      float v = (bf2f(rowbuf[wave][g * ODIM + o]) - mean) * inv;
      zn[g] = v * gamma[g * ODIM + o] + beta[g * ODIM + o];
    }
    const float fg = 1.f / (1.f + expf(-zn[0]));
    const float ig = 1.f / (1.f + expf(-zn[1]));
    const float og = 1.f / (1.f + expf(-zn[2]));
    const float x = zn[3];
    const float hs = 0.5f * x * (1.f + erff(x * 0.70710678118654752f));
    const float cc = fg * cr[j] + ig * hs;
    __builtin_nontemporal_store(cc, out_c + o);
    __builtin_nontemporal_store(og * cc, out_o + o);
  }
}

// ---------------- launch ----------------

extern "C" void kernel_launch(void* const* d_in, const int* in_sizes, int n_in,
                              void* d_out, int out_size, void* d_ws, size_t ws_size,
                              hipStream_t stream) {
  const float* input = (const float*)d_in[0];
  const float* h     = (const float*)d_in[1];
  const float* c     = (const float*)d_in[2];
  const float* W     = (const float*)d_in[3];
  const float* gamma = (const float*)d_in[4];
  const float* beta  = (const float*)d_in[5];

  unsigned short* A  = (unsigned short*)d_ws;                 // [32768,1024] bf16
  unsigned short* Wb = A + (size_t)BDIM * KDIM;               // [2048,1024] bf16
  unsigned short* z  = Wb + (size_t)NDIM * KDIM;              // [32768,2048] bf16
  float* out = (float*)d_out;

  hipFuncSetAttribute((const void*)gemm_kernel,
                      hipFuncAttributeMaxDynamicSharedMemorySize, 131072);

  pack_ab_kernel<<<16384 + 1024, 256, 0, stream>>>(input, h, W, A, Wb);
  gemm_kernel<<<dim3((BDIM / 256) * (NDIM / 256)), 512, 131072, stream>>>(A, Wb, z);
  ln_gate_kernel<<<BDIM / 8, 512, 0, stream>>>(z, c, gamma, beta, out);
}